// Round 1
// baseline (358.281 us; speedup 1.0000x reference)
//
#include <hip/hip_runtime.h>
#include <math.h>

// ChannelDropout: out[b,c,t] = x[b,c,t] * scale[b,c]
// scale = (valid && dist(pos, center0) > 0.1) ? 1/(prob_kept + 1e-8) : 0
// prob_kept = mean over centers 1..N-1 of (dist > 0.1)
// valid = !(pos == (-2,-2))
//
// v2 (no-barrier): one block per (b,c) row. EVERY wave computes the row
// scale redundantly — lane-parallel over the MC centers, then a
// __shfl_xor butterfly so all 64 lanes hold the count. This removes the
// LDS broadcast + __syncthreads of v1, so the 750 float4 x-loads
// (issued FIRST, below) overlap the pos/centers dependency chain instead
// of the whole block stalling behind wave 0's serial prologue.
// Stores are nontemporal: out is write-once, don't evict x from L2/L3.

typedef float f32x4 __attribute__((ext_vector_type(4)));

__global__ __launch_bounds__(256) void ChannelDropout_14851996910142_kernel(
    const float* __restrict__ x,
    const float* __restrict__ pos,
    const float* __restrict__ centers,
    float* __restrict__ out,
    int ncenters, int tlen)
{
    const int row  = blockIdx.x;
    const int tid  = threadIdx.x;
    const int lane = tid & 63;

    const size_t base = (size_t)row * (size_t)tlen;
    const int t4 = tlen >> 2;                    // 750 float4 per row
    const f32x4* __restrict__ xr   = (const f32x4*)(x + base);
    f32x4* __restrict__       orow = (f32x4*)(out + base);

    // ---- issue the bulk HBM loads first (3 float4/thread covers t4<=768)
    const int i0 = tid, i1 = tid + 256, i2 = tid + 512;
    const bool p0 = i0 < t4, p1 = i1 < t4, p2 = i2 < t4;
    f32x4 v0 = {}, v1 = {}, v2 = {};
    if (p0) v0 = xr[i0];
    if (p1) v1 = xr[i1];
    if (p2) v2 = xr[i2];

    // ---- per-wave scale (uniform per row; redundant across the 4 waves)
    const float px = pos[2 * row];
    const float py = pos[2 * row + 1];
    const bool valid = !(px == -2.0f && py == -2.0f);

    float cnt = 0.0f;
    for (int c = 1 + lane; c < ncenters; c += 64) {
        const float dx = px - centers[2 * c];
        const float dy = py - centers[2 * c + 1];
        // match np: d = sqrt(dx*dx + dy*dy), no fma contraction
        const float d2 = __fadd_rn(__fmul_rn(dx, dx), __fmul_rn(dy, dy));
        cnt += (sqrtf(d2) > 0.1f) ? 1.0f : 0.0f;
    }
    // butterfly: ALL lanes end with the full sum (exact: integer-valued fp32)
    #pragma unroll
    for (int off = 32; off > 0; off >>= 1)
        cnt += __shfl_xor(cnt, off, 64);

    const float dx0 = px - centers[0];
    const float dy0 = py - centers[1];
    const float d02 = __fadd_rn(__fmul_rn(dx0, dx0), __fmul_rn(dy0, dy0));
    const bool kept0 = sqrtf(d02) > 0.1f;
    const float prob = cnt / (float)(ncenters - 1);
    const float s = (valid && kept0) ? (1.0f / (prob + 1e-8f)) : 0.0f;

    // ---- scaled streaming stores (nontemporal, write-once)
    if (p0) __builtin_nontemporal_store(v0 * s, orow + i0);
    if (p1) __builtin_nontemporal_store(v1 * s, orow + i1);
    if (p2) __builtin_nontemporal_store(v2 * s, orow + i2);

    // generic tails (not taken for tlen = 3000)
    for (int i = tid + 768; i < t4; i += 256) {
        f32x4 v = xr[i];
        __builtin_nontemporal_store(v * s, orow + i);
    }
    for (int i = (t4 << 2) + tid; i < tlen; i += 256) {
        out[base + i] = x[base + i] * s;
    }
}

extern "C" void kernel_launch(void* const* d_in, const int* in_sizes, int n_in,
                              void* d_out, int out_size, void* d_ws, size_t ws_size,
                              hipStream_t stream) {
    const float* x       = (const float*)d_in[0];   // [B, C, T]
    const float* pos     = (const float*)d_in[1];   // [B, C, 2]
    const float* centers = (const float*)d_in[2];   // [N, 2]
    float* out = (float*)d_out;

    const int rows     = in_sizes[1] / 2;       // B*C = 17600
    const int tlen     = in_sizes[0] / rows;    // T = 3000
    const int ncenters = in_sizes[2] / 2;       // 101

    ChannelDropout_14851996910142_kernel<<<rows, 256, 0, stream>>>(
        x, pos, centers, out, ncenters, tlen);
}